// Round 7
// baseline (361.845 us; speedup 1.0000x reference)
//
#include <hip/hip_runtime.h>
#include <hip/hip_bf16.h>
#include <math.h>

#define DM    2048
#define DQKV  6144
#define NH    16
#define DH    128
#define TT    1024
#define BB    4

typedef __bf16 bf16_t;
typedef __bf16 bf16x4 __attribute__((ext_vector_type(4)));
typedef __bf16 bf16x8 __attribute__((ext_vector_type(8)));
typedef float  f32x4  __attribute__((ext_vector_type(4)));

__device__ __forceinline__ void async16(const void* g, void* lds) {
  __builtin_amdgcn_global_load_lds(
      (const __attribute__((address_space(1))) unsigned int*)g,
      (__attribute__((address_space(3))) unsigned int*)lds, 16, 0, 0);
}

// raw s_barrier with compiler memory fences (no vmcnt/lgkm drain emitted)
__device__ __forceinline__ void block_barrier() {
  asm volatile("" ::: "memory");
  __builtin_amdgcn_s_barrier();
  asm volatile("" ::: "memory");
}

// ---------------------------------------------------------------------------
// PREP (fused, 1 launch): blocks [0,4096) cast x->xb; [4096,7168) transpose
// w_qkv; [7168,8192) transpose w_out.
// ---------------------------------------------------------------------------
__global__ __launch_bounds__(256) void prep_kernel(
    const float* __restrict__ x, bf16_t* __restrict__ xb,
    const float* __restrict__ w_qkv, bf16_t* __restrict__ wqkv_t,
    const float* __restrict__ w_out, bf16_t* __restrict__ wout_t) {
  const int tid = threadIdx.x;
  const int bx = blockIdx.x;
  if (bx < 4096) {  // cast fp32 -> bf16, 8 elems/thread
    const size_t i = ((size_t)bx * 256 + tid) * 8;
    float4 a = *(const float4*)(x + i);
    float4 b = *(const float4*)(x + i + 4);
    bf16x8 o = {(bf16_t)a.x, (bf16_t)a.y, (bf16_t)a.z, (bf16_t)a.w,
                (bf16_t)b.x, (bf16_t)b.y, (bf16_t)b.z, (bf16_t)b.w};
    *(bf16x8*)(xb + i) = o;
    return;
  }
  // W[K][N] fp32 -> Wt[N][K] bf16, 64x64 tiles
  __shared__ bf16_t tile[64][72];
  const float* W;
  bf16_t* Wt;
  int K, N, tn, tk;
  if (bx < 7168) {
    const int t = bx - 4096;
    W = w_qkv; Wt = wqkv_t; K = 2048; N = 6144;
    tn = (t % 96) * 64; tk = (t / 96) * 64;
  } else {
    const int t = bx - 7168;
    W = w_out; Wt = wout_t; K = 2048; N = 2048;
    tn = (t % 32) * 64; tk = (t / 32) * 64;
  }
  {
    int r = tid >> 2, c0 = (tid & 3) * 16;
    const float* src = W + (size_t)(tk + r) * N + tn + c0;
#pragma unroll
    for (int j = 0; j < 4; ++j) {
      float4 v = *(const float4*)(src + j * 4);
      tile[r][c0 + j * 4 + 0] = (bf16_t)v.x;
      tile[r][c0 + j * 4 + 1] = (bf16_t)v.y;
      tile[r][c0 + j * 4 + 2] = (bf16_t)v.z;
      tile[r][c0 + j * 4 + 3] = (bf16_t)v.w;
    }
  }
  __syncthreads();
  {
    int n = tid >> 2, c0 = (tid & 3) * 16;
    bf16_t* dst = Wt + (size_t)(tn + n) * K + tk + c0;
#pragma unroll
    for (int j = 0; j < 4; ++j) {
      bf16x4 t = {tile[c0 + j * 4 + 0][n], tile[c0 + j * 4 + 1][n],
                  tile[c0 + j * 4 + 2][n], tile[c0 + j * 4 + 3][n]};
      *(bf16x4*)(dst + j * 4) = t;
    }
  }
}

// ---------------------------------------------------------------------------
// V transpose (FALLBACK only, when ws too small for non-aliased Vt_g).
// ---------------------------------------------------------------------------
__global__ __launch_bounds__(256) void v_transpose_kernel(
    const bf16_t* __restrict__ qkv, bf16_t* __restrict__ Vt_g) {
  __shared__ bf16_t tile[64][72];
  const int tid = threadIdx.x;
  const int dt = blockIdx.x;
  const int tt = blockIdx.y;
  const int bh = blockIdx.z;
  const int b = bh >> 4, h = bh & 15;
  {
    int r = tid >> 2, c0 = (tid & 3) * 16;
    const bf16_t* src =
        qkv + (size_t)(b * TT + tt * 64 + r) * DQKV + 2 * DM + h * DH + dt * 64 + c0;
    *(bf16x8*)&tile[r][c0]     = *(const bf16x8*)(src);
    *(bf16x8*)&tile[r][c0 + 8] = *(const bf16x8*)(src + 8);
  }
  __syncthreads();
  {
    int n = tid >> 2, c0 = (tid & 3) * 16;
    bf16_t* dst = Vt_g + (size_t)(bh * DH + dt * 64 + n) * TT + tt * 64 + c0;
#pragma unroll
    for (int j = 0; j < 4; ++j) {
      bf16x4 t = {tile[c0 + j * 4 + 0][n], tile[c0 + j * 4 + 1][n],
                  tile[c0 + j * 4 + 2][n], tile[c0 + j * 4 + 3][n]};
      *(bf16x4*)(dst + j * 4) = t;
    }
  }
}

// ---------------------------------------------------------------------------
// GEMM 256 x (BCH*64), BK=64, 512 thr / 8 waves (2M x 4N), per-wave
// 128 x BCH*16.  v2 K-loop: INTERLEAVED CLUSTERS + SPLIT STAGING.
//
// Old structure serialized [22 ds_reads | lgkm0 | BAR] then [48 MFMA]: the
// barrier sat between the LDS pipe and the matrix pipe (per-tile ~= reads
// 1408cy + MFMA 1862cy + ~1100cy sync = 4387cy measured). New structure: 4
// read+MFMA clusters (M-half x K-half; 22 reads total, B regs held per
// K-half) with NO barrier between reads and MFMAs -> compiler can hoist
// cluster k+1's ds_reads under cluster k's MFMAs (separate pipes).
// Staging split by region deadness:
//   Y = {a0,a2} (M-half0 rows {0-63,128-191}) of tile kt+1 -> buf[cur^1]:
//       that region was last read in tile kt-1 -> no sync needed; issued
//       early in the body (full tile of latency cover).
//   Z = {a1,a3,b*} of tile kt+2 -> buf[cur]: needs all waves' reads of
//       buf[cur] done -> after lgkmcnt(0)+BAR at end of body.
// One vmcnt(2+BCH) per tile (after Z): retires X(kt+1)+Y(kt+1) -> tile kt+1
// fully resident; Z stays in flight. Never drains to 0 mid-loop.
// lgkmcnt(0) before BAR = rule-18 guard (no wave crosses with reads
// outstanding while others stage over the rows).
// ---------------------------------------------------------------------------
template <bool OUT_BF16, int BCH, bool WRITE_VT>
__global__ __launch_bounds__(512, 2) void gemm_big_kernel(
    const bf16_t* __restrict__ A, const bf16_t* __restrict__ Bt,
    const float* __restrict__ bias, void* __restrict__ out,
    bf16_t* __restrict__ vt, int M, int N, int K, int nbm) {
  __shared__ __align__(16) bf16_t As[2][256 * 64];
  __shared__ __align__(16) bf16_t Bs[2][BCH * 64 * 64];

  const int tid  = threadIdx.x;
  const int lane = tid & 63;
  const int wave = tid >> 6;
  const int ln   = lane & 15;
  const int quad = lane >> 4;

  // XCD-aware swizzle (gridDim.x % 8 == 0)
  const int cpx = gridDim.x >> 3;
  const int wg  = (blockIdx.x & 7) * cpx + (blockIdx.x >> 3);
  const int bm  = wg & (nbm - 1);
  const int bn  = wg / nbm;

  const bf16_t* Abase = A + (size_t)bm * 256 * K;
  const bf16_t* Bbase = Bt + (size_t)bn * (BCH * 64) * K;

  const int m0 = (wave >> 2) * 128;       // 2 M-waves
  const int n0 = (wave & 3) * (BCH * 16); // 4 N-waves

  f32x4 acc[8][BCH] = {};

  const int NT = K >> 6;

  // stage one 64-row chunk (s) of A / B for K-tile kt into buffer d
  auto sA = [&](int kt, int d, int s) {
    const int fb  = s * 512 + wave * 64;
    const int f   = fb + lane;
    const int row = f >> 3, c = f & 7;
    const int gc  = c ^ (row & 7);
    async16(Abase + (size_t)row * K + kt * 64 + gc * 8,
            (char*)(&As[d][0]) + fb * 16);
  };
  auto sB = [&](int kt, int d, int s) {
    const int fb  = s * 512 + wave * 64;
    const int f   = fb + lane;
    const int row = f >> 3, c = f & 7;
    const int gc  = c ^ (row & 7);
    async16(Bbase + (size_t)row * K + kt * 64 + gc * 8,
            (char*)(&Bs[d][0]) + fb * 16);
  };
  auto vm_steady = [&] {
    if constexpr (BCH == 3)
      asm volatile("s_waitcnt vmcnt(5)" ::: "memory");
    else
      asm volatile("s_waitcnt vmcnt(4)" ::: "memory");
  };

  // prologue: tile0 complete -> buf0; tile1 {a1,a3,b*} -> buf1.
  // (tile1's {a0,a2} are the Y-slot of tile0's body.)
#pragma unroll
  for (int s = 0; s < 4; ++s) sA(0, 0, s);
#pragma unroll
  for (int s = 0; s < BCH; ++s) sB(0, 0, s);
  sA(1, 1, 1);
  sA(1, 1, 3);
#pragma unroll
  for (int s = 0; s < BCH; ++s) sB(1, 1, s);
  vm_steady();  // retires tile0's 4+BCH loads; tile1's 2+BCH stay in flight
  block_barrier();

  for (int kt = 0; kt < NT; ++kt) {
    const int cur = kt & 1;
    const char* cA = (const char*)(&As[cur][0]);
    const char* cB = (const char*)(&Bs[cur][0]);
    bf16x8 a[4], brg[BCH];

    // ---- cluster 1: M-half0 x ks0 (loads B ks0) ----
#pragma unroll
    for (int i = 0; i < 4; ++i) {
      const int row = m0 + 16 * i + ln;
      const int c = quad ^ (row & 7);
      a[i] = *(const bf16x8*)(cA + ((row * 8 + c) << 4));
    }
#pragma unroll
    for (int j = 0; j < BCH; ++j) {
      const int row = n0 + 16 * j + ln;
      const int c = quad ^ (row & 7);
      brg[j] = *(const bf16x8*)(cB + ((row * 8 + c) << 4));
    }
    // Y-stage: tile kt+1's M-half0 chunks into buf[cur^1] (region dead
    // since tile kt-1; no sync needed; full tile of latency cover).
    if (kt + 1 < NT) {
      sA(kt + 1, cur ^ 1, 0);
      sA(kt + 1, cur ^ 1, 2);
    }
    __builtin_amdgcn_s_setprio(1);
#pragma unroll
    for (int i = 0; i < 4; ++i)
#pragma unroll
      for (int j = 0; j < BCH; ++j)
        acc[i][j] = __builtin_amdgcn_mfma_f32_16x16x32_bf16(a[i], brg[j],
                                                            acc[i][j], 0, 0, 0);
    __builtin_amdgcn_s_setprio(0);

    // ---- cluster 2: M-half1 x ks0 (B held) ----
#pragma unroll
    for (int i = 0; i < 4; ++i) {
      const int row = m0 + 64 + 16 * i + ln;
      const int c = quad ^ (row & 7);
      a[i] = *(const bf16x8*)(cA + ((row * 8 + c) << 4));
    }
    __builtin_amdgcn_s_setprio(1);
#pragma unroll
    for (int i = 0; i < 4; ++i)
#pragma unroll
      for (int j = 0; j < BCH; ++j)
        acc[4 + i][j] = __builtin_amdgcn_mfma_f32_16x16x32_bf16(
            a[i], brg[j], acc[4 + i][j], 0, 0, 0);
    __builtin_amdgcn_s_setprio(0);

    // ---- cluster 3: M-half1 x ks1 (loads B ks1) ----
#pragma unroll
    for (int i = 0; i < 4; ++i) {
      const int row = m0 + 64 + 16 * i + ln;
      const int c = (4 + quad) ^ (row & 7);
      a[i] = *(const bf16x8*)(cA + ((row * 8 + c) << 4));
    }
#pragma unroll
    for (int j = 0; j < BCH; ++j) {
      const int row = n0 + 16 * j + ln;
      const int c = (4 + quad) ^ (row & 7);
      brg[j] = *(const bf16x8*)(cB + ((row * 8 + c) << 4));
    }
    __builtin_amdgcn_s_setprio(1);
#pragma unroll
    for (int i = 0; i < 4; ++i)
#pragma unroll
      for (int j = 0; j < BCH; ++j)
        acc[4 + i][j] = __builtin_amdgcn_mfma_f32_16x16x32_bf16(
            a[i], brg[j], acc[4 + i][j], 0, 0, 0);
    __builtin_amdgcn_s_setprio(0);

    // ---- cluster 4: M-half0 x ks1 (B held) ----
#pragma unroll
    for (int i = 0; i < 4; ++i) {
      const int row = m0 + 16 * i + ln;
      const int c = (4 + quad) ^ (row & 7);
      a[i] = *(const bf16x8*)(cA + ((row * 8 + c) << 4));
    }
    __builtin_amdgcn_s_setprio(1);
#pragma unroll
    for (int i = 0; i < 4; ++i)
#pragma unroll
      for (int j = 0; j < BCH; ++j)
        acc[i][j] = __builtin_amdgcn_mfma_f32_16x16x32_bf16(a[i], brg[j],
                                                            acc[i][j], 0, 0, 0);
    __builtin_amdgcn_s_setprio(0);

    // all of this wave's ds_reads of buf[cur] executed before crossing
    asm volatile("s_waitcnt lgkmcnt(0)" ::: "memory");
    block_barrier();  // ALL waves done reading buf[cur]

    // Z-stage: tile kt+2's {a1,a3,b*} into buf[cur] (regions now dead)
    if (kt + 2 < NT) {
      sA(kt + 2, cur, 1);
      sA(kt + 2, cur, 3);
#pragma unroll
      for (int s = 0; s < BCH; ++s) sB(kt + 2, cur, s);
    }
    if (kt + 2 < NT)
      vm_steady();  // retires X(kt+1)+Y(kt+1): tile kt+1 fully resident
    else if (kt == NT - 2)
      asm volatile("s_waitcnt vmcnt(0)" ::: "memory");  // drain for last tile
    block_barrier();
  }

#pragma unroll
  for (int i = 0; i < 8; ++i) {
    const int rowg = bm * 256 + m0 + 16 * i + quad * 4;
#pragma unroll
    for (int j = 0; j < BCH; ++j) {
      const int cb   = bn * (BCH * 64) + n0 + 16 * j;  // wave-uniform
      const int colg = cb + ln;
      const float bb = bias[colg];
      if (WRITE_VT && cb >= 2 * DM) {
        // V third: transposed write into Vt_g[(b*16+h)*128+d][t]
        const int vrow = ((rowg >> 10) << 11) + (colg - 2 * DM);
        bf16x4 v = {(bf16_t)(acc[i][j][0] + bb), (bf16_t)(acc[i][j][1] + bb),
                    (bf16_t)(acc[i][j][2] + bb), (bf16_t)(acc[i][j][3] + bb)};
        *(bf16x4*)(vt + (size_t)vrow * TT + (rowg & (TT - 1))) = v;
      } else {
#pragma unroll
        for (int r = 0; r < 4; ++r) {
          float val = acc[i][j][r] + bb;
          if (OUT_BF16)
            ((bf16_t*)out)[(size_t)(rowg + r) * N + colg] = (bf16_t)val;
          else
            ((float*)out)[(size_t)(rowg + r) * N + colg] = val;
        }
      }
    }
  }
}

// ---------------------------------------------------------------------------
// Flash attention, causal, FIXED-SHIFT softmax. 256 thr / 4 waves / QBLK=64 /
// KVBLK=64, dbuf K/V, issue-early staging, counted vmcnt(8), snake qt mapping.
// ---------------------------------------------------------------------------
__global__ __launch_bounds__(256, 2) void attn_kernel(
    const bf16_t* __restrict__ qkv, const bf16_t* __restrict__ Vt_g,
    bf16_t* __restrict__ attout) {
  const int bx = blockIdx.x;
  const int bh = bx & 63;
  const int j_  = bx >> 6;
  const int rr  = j_ >> 2, cc_ = j_ & 3;
  const int qt  = (rr & 1) ? (rr * 4 + (3 - cc_)) : (rr * 4 + cc_);
  const int b  = bh >> 4;
  const int h  = bh & 15;
  const int tid  = threadIdx.x;
  const int lane = tid & 63;
  const int wave = tid >> 6;
  const int ln   = lane & 15;
  const int quad = lane >> 4;

  __shared__ __align__(16) bf16_t Ks[2][64 * 128];
  __shared__ __align__(16) bf16_t Vs[2][128 * 64];
  __shared__ __align__(16) bf16_t Ps[4 * 16 * 64];

  const float scale = 0.08838834764831845f;
  const float SHIFT = 12.0f;
  const int q0 = qt * 64 + wave * 16;

  bf16x8 aq[4];
  {
    const bf16_t* qrow = qkv + (size_t)(b * TT + q0 + ln) * DQKV + h * DH;
#pragma unroll
    for (int kt = 0; kt < 4; ++kt)
      aq[kt] = *(const bf16x8*)(qrow + kt * 32 + quad * 8);
  }

  auto stage = [&](int c, int buf) {
    const int kc = c * 64;
#pragma unroll
    for (int j = 0; j < 4; ++j) {
      const int fb = j * 256 + wave * 64;
      const int l  = fb + lane;
      {
        const int row = l >> 4, cc = l & 15;
        const int gc  = cc ^ (row & 7);
        const bf16_t* g =
            qkv + (size_t)(b * TT + kc + row) * DQKV + DM + h * DH + gc * 8;
        async16(g, (char*)(&Ks[buf][0]) + fb * 16);
      }
      {
        const int d = l >> 3, cc = l & 7;
        const int gc = cc ^ (d & 7);
        const bf16_t* g = Vt_g + (size_t)(bh * DH + d) * TT + kc + gc * 8;
        async16(g, (char*)(&Vs[buf][0]) + fb * 16);
      }
    }
  };

  f32x4 o[8] = {};
  float lp[4] = {0.f, 0.f, 0.f, 0.f};

  stage(0, 0);

  for (int c = 0; c <= qt; ++c) {
    const int cur = c & 1;
    const char* Kc = (const char*)(&Ks[cur][0]);
    const char* Vc = (const char*)(&Vs[cur][0]);

    asm volatile("s_waitcnt lgkmcnt(0)" ::: "memory");
    block_barrier();
    if (c < qt) {
      stage(c + 1, cur ^ 1);
      asm volatile("s_waitcnt vmcnt(8)" ::: "memory");
    } else {
      asm volatile("s_waitcnt vmcnt(0)" ::: "memory");
    }
    block_barrier();

    f32x4 sacc[4];
    __builtin_amdgcn_s_setprio(1);
#pragma unroll
    for (int jt = 0; jt < 4; ++jt) {
      sacc[jt] = (f32x4){0.f, 0.f, 0.f, 0.f};
#pragma unroll
      for (int kt = 0; kt < 4; ++kt) {
        const int row = jt * 16 + ln;
        const int sc  = (kt * 4 + quad) ^ (row & 7);
        bf16x8 bk = *(const bf16x8*)(Kc + row * 256 + sc * 16);
        sacc[jt] = __builtin_amdgcn_mfma_f32_16x16x32_bf16(aq[kt], bk,
                                                           sacc[jt], 0, 0, 0);
      }
    }
    __builtin_amdgcn_s_setprio(0);

    const int kc = c * 64;
    const bool diag = (c == qt);
#pragma unroll
    for (int jt = 0; jt < 4; ++jt) {
      const int colg = kc + jt * 16 + ln;
#pragma unroll
      for (int r = 0; r < 4; ++r) {
        float sv = sacc[jt][r] * scale - SHIFT;
        if (diag && colg > q0 + quad * 4 + r) sv = -1e30f;
        float pv = __expf(sv);
        lp[r] += pv;
        const int row = quad * 4 + r;
        const int col = jt * 16 + ln;
        const int sc  = (col >> 3) ^ (row & 7);
        Ps[wave * 1024 + row * 64 + sc * 8 + (col & 7)] = (bf16_t)pv;
      }
    }

    __builtin_amdgcn_s_setprio(1);
#pragma unroll
    for (int ks = 0; ks < 2; ++ks) {
      const int psc = (ks * 4 + quad) ^ (ln & 7);
      bf16x8 ap =
          *(const bf16x8*)((const char*)Ps + wave * 2048 + ln * 128 + psc * 16);
#pragma unroll
      for (int nt = 0; nt < 8; ++nt) {
        const int row = nt * 16 + ln;
        const int sc  = (ks * 4 + quad) ^ (row & 7);
        bf16x8 bv = *(const bf16x8*)(Vc + row * 128 + sc * 16);
        o[nt] = __builtin_amdgcn_mfma_f32_16x16x32_bf16(ap, bv, o[nt], 0, 0, 0);
      }
    }
    __builtin_amdgcn_s_setprio(0);
  }

#pragma unroll
  for (int off = 1; off < 16; off <<= 1)
#pragma unroll
    for (int r = 0; r < 4; ++r) lp[r] += __shfl_xor(lp[r], off, 64);

#pragma unroll
  for (int r = 0; r < 4; ++r) {
    float inv = 1.0f / lp[r];
    int t = q0 + quad * 4 + r;
    bf16_t* orow = attout + (size_t)(b * TT + t) * DM + h * DH;
#pragma unroll
    for (int nt = 0; nt < 8; ++nt)
      orow[nt * 16 + ln] = (bf16_t)(o[nt][r] * inv);
  }
}

// ---------------------------------------------------------------------------
extern "C" void kernel_launch(void* const* d_in, const int* in_sizes, int n_in,
                              void* d_out, int out_size, void* d_ws,
                              size_t ws_size, hipStream_t stream) {
  const float* x     = (const float*)d_in[0];
  const float* w_qkv = (const float*)d_in[1];
  const float* b_qkv = (const float*)d_in[2];
  const float* w_out = (const float*)d_in[3];
  const float* b_out = (const float*)d_in[4];
  float* out = (float*)d_out;

  char* ws = (char*)d_ws;
  bf16_t* qkv    = (bf16_t*)(ws);
  bf16_t* wqkv_t = (bf16_t*)(ws + 50331648);
  bf16_t* wout_t = (bf16_t*)(ws + 75497472);
  bf16_t* xb     = (bf16_t*)(ws + 83886080);
  bf16_t* attout = xb;

  const bool fuse_vt = (ws_size >= 117440512);
  bf16_t* Vt_g = fuse_vt ? (bf16_t*)(ws + 100663296) : wqkv_t;

  prep_kernel<<<dim3(8192), dim3(256), 0, stream>>>(x, xb, w_qkv, wqkv_t,
                                                    w_out, wout_t);
  if (fuse_vt) {
    gemm_big_kernel<true, 3, true><<<dim3(512), dim3(512), 0, stream>>>(
        xb, wqkv_t, b_qkv, qkv, Vt_g, 4096, 6144, 2048, 16);
  } else {
    gemm_big_kernel<true, 3, false><<<dim3(512), dim3(512), 0, stream>>>(
        xb, wqkv_t, b_qkv, qkv, nullptr, 4096, 6144, 2048, 16);
    v_transpose_kernel<<<dim3(2, 16, 64), dim3(256), 0, stream>>>(qkv, Vt_g);
  }
  attn_kernel<<<dim3(1024), dim3(256), 0, stream>>>(qkv, Vt_g, attout);
  gemm_big_kernel<false, 2, false><<<dim3(256), dim3(512), 0, stream>>>(
      attout, wout_t, b_out, out, nullptr, 4096, 2048, 2048, 16);
}

// Round 8
// 332.110 us; speedup vs baseline: 1.0895x; 1.0895x over previous
//
#include <hip/hip_runtime.h>
#include <hip/hip_bf16.h>
#include <math.h>

#define DM    2048
#define DQKV  6144
#define NH    16
#define DH    128
#define TT    1024
#define BB    4

typedef __bf16 bf16_t;
typedef __bf16 bf16x4 __attribute__((ext_vector_type(4)));
typedef __bf16 bf16x8 __attribute__((ext_vector_type(8)));
typedef float  f32x4  __attribute__((ext_vector_type(4)));

__device__ __forceinline__ void async16(const void* g, void* lds) {
  __builtin_amdgcn_global_load_lds(
      (const __attribute__((address_space(1))) unsigned int*)g,
      (__attribute__((address_space(3))) unsigned int*)lds, 16, 0, 0);
}

// raw s_barrier with compiler memory fences (no vmcnt/lgkm drain emitted)
__device__ __forceinline__ void block_barrier() {
  asm volatile("" ::: "memory");
  __builtin_amdgcn_s_barrier();
  asm volatile("" ::: "memory");
}

// ---------------------------------------------------------------------------
// PREP (fused, 1 launch): blocks [0,4096) cast x->xb; [4096,7168) transpose
// w_qkv; [7168,8192) transpose w_out.
// ---------------------------------------------------------------------------
__global__ __launch_bounds__(256) void prep_kernel(
    const float* __restrict__ x, bf16_t* __restrict__ xb,
    const float* __restrict__ w_qkv, bf16_t* __restrict__ wqkv_t,
    const float* __restrict__ w_out, bf16_t* __restrict__ wout_t) {
  const int tid = threadIdx.x;
  const int bx = blockIdx.x;
  if (bx < 4096) {  // cast fp32 -> bf16, 8 elems/thread
    const size_t i = ((size_t)bx * 256 + tid) * 8;
    float4 a = *(const float4*)(x + i);
    float4 b = *(const float4*)(x + i + 4);
    bf16x8 o = {(bf16_t)a.x, (bf16_t)a.y, (bf16_t)a.z, (bf16_t)a.w,
                (bf16_t)b.x, (bf16_t)b.y, (bf16_t)b.z, (bf16_t)b.w};
    *(bf16x8*)(xb + i) = o;
    return;
  }
  // W[K][N] fp32 -> Wt[N][K] bf16, 64x64 tiles
  __shared__ bf16_t tile[64][72];
  const float* W;
  bf16_t* Wt;
  int K, N, tn, tk;
  if (bx < 7168) {
    const int t = bx - 4096;
    W = w_qkv; Wt = wqkv_t; K = 2048; N = 6144;
    tn = (t % 96) * 64; tk = (t / 96) * 64;
  } else {
    const int t = bx - 7168;
    W = w_out; Wt = wout_t; K = 2048; N = 2048;
    tn = (t % 32) * 64; tk = (t / 32) * 64;
  }
  {
    int r = tid >> 2, c0 = (tid & 3) * 16;
    const float* src = W + (size_t)(tk + r) * N + tn + c0;
#pragma unroll
    for (int j = 0; j < 4; ++j) {
      float4 v = *(const float4*)(src + j * 4);
      tile[r][c0 + j * 4 + 0] = (bf16_t)v.x;
      tile[r][c0 + j * 4 + 1] = (bf16_t)v.y;
      tile[r][c0 + j * 4 + 2] = (bf16_t)v.z;
      tile[r][c0 + j * 4 + 3] = (bf16_t)v.w;
    }
  }
  __syncthreads();
  {
    int n = tid >> 2, c0 = (tid & 3) * 16;
    bf16_t* dst = Wt + (size_t)(tn + n) * K + tk + c0;
#pragma unroll
    for (int j = 0; j < 4; ++j) {
      bf16x4 t = {tile[c0 + j * 4 + 0][n], tile[c0 + j * 4 + 1][n],
                  tile[c0 + j * 4 + 2][n], tile[c0 + j * 4 + 3][n]};
      *(bf16x4*)(dst + j * 4) = t;
    }
  }
}

// ---------------------------------------------------------------------------
// V transpose (FALLBACK only, when ws too small for non-aliased Vt_g).
// ---------------------------------------------------------------------------
__global__ __launch_bounds__(256) void v_transpose_kernel(
    const bf16_t* __restrict__ qkv, bf16_t* __restrict__ Vt_g) {
  __shared__ bf16_t tile[64][72];
  const int tid = threadIdx.x;
  const int dt = blockIdx.x;
  const int tt = blockIdx.y;
  const int bh = blockIdx.z;
  const int b = bh >> 4, h = bh & 15;
  {
    int r = tid >> 2, c0 = (tid & 3) * 16;
    const bf16_t* src =
        qkv + (size_t)(b * TT + tt * 64 + r) * DQKV + 2 * DM + h * DH + dt * 64 + c0;
    *(bf16x8*)&tile[r][c0]     = *(const bf16x8*)(src);
    *(bf16x8*)&tile[r][c0 + 8] = *(const bf16x8*)(src + 8);
  }
  __syncthreads();
  {
    int n = tid >> 2, c0 = (tid & 3) * 16;
    bf16_t* dst = Vt_g + (size_t)(bh * DH + dt * 64 + n) * TT + tt * 64 + c0;
#pragma unroll
    for (int j = 0; j < 4; ++j) {
      bf16x4 t = {tile[c0 + j * 4 + 0][n], tile[c0 + j * 4 + 1][n],
                  tile[c0 + j * 4 + 2][n], tile[c0 + j * 4 + 3][n]};
      *(bf16x4*)(dst + j * 4) = t;
    }
  }
}

// ---------------------------------------------------------------------------
// GEMM 256 x (BCH*64), BK=64, 512 thr / 8 waves (2M x 4N).
// VERIFIED counted-vmcnt schedule (899 TF; rounds 1/3/4/6). Per K-tile:
// front-load all ds_read operands -> lgkmcnt(0) -> barrier (seals all reads
// of buf[cur]) -> stage A(kt+2) -> MFMA ks0 -> stage B(kt+2) -> MFMA ks1 ->
// vmcnt(LPT) -> barrier. Tail drains vmcnt(0). Do NOT restructure this loop:
// the 8-phase (r2), and interleaved-cluster (r7) variants both regressed
// ~20% (140 / 137 us vs 114-118 us here).
// WRITE_VT: V-third columns written transposed into Vt_g (fuses the old
// v_transpose kernel; measured net win in r6).
// ---------------------------------------------------------------------------
template <bool OUT_BF16, int BCH, bool WRITE_VT>
__global__ __launch_bounds__(512, 2) void gemm_big_kernel(
    const bf16_t* __restrict__ A, const bf16_t* __restrict__ Bt,
    const float* __restrict__ bias, void* __restrict__ out,
    bf16_t* __restrict__ vt, int M, int N, int K, int nbm) {
  __shared__ __align__(16) bf16_t As[2][256 * 64];
  __shared__ __align__(16) bf16_t Bs[2][BCH * 64 * 64];

  const int tid  = threadIdx.x;
  const int lane = tid & 63;
  const int wave = tid >> 6;
  const int ln   = lane & 15;
  const int quad = lane >> 4;

  // XCD-aware swizzle (gridDim.x % 8 == 0)
  const int cpx = gridDim.x >> 3;
  const int wg  = (blockIdx.x & 7) * cpx + (blockIdx.x >> 3);
  const int bm  = wg & (nbm - 1);
  const int bn  = wg / nbm;

  const bf16_t* Abase = A + (size_t)bm * 256 * K;
  const bf16_t* Bbase = Bt + (size_t)bn * (BCH * 64) * K;

  const int m0 = (wave >> 2) * 128;       // 2 M-waves
  const int n0 = (wave & 3) * (BCH * 16); // 4 N-waves

  f32x4 acc[8][BCH] = {};

  const int NT = K >> 6;

  auto stageA = [&](int kt, int d) {
#pragma unroll
    for (int s = 0; s < 4; ++s) {
      const int fb  = s * 512 + wave * 64;
      const int f   = fb + lane;
      const int row = f >> 3, c = f & 7;
      const int gc  = c ^ (row & 7);
      async16(Abase + (size_t)row * K + kt * 64 + gc * 8,
              (char*)(&As[d][0]) + fb * 16);
    }
  };
  auto stageB = [&](int kt, int d) {
#pragma unroll
    for (int s = 0; s < BCH; ++s) {
      const int fb  = s * 512 + wave * 64;
      const int f   = fb + lane;
      const int row = f >> 3, c = f & 7;
      const int gc  = c ^ (row & 7);
      async16(Bbase + (size_t)row * K + kt * 64 + gc * 8,
              (char*)(&Bs[d][0]) + fb * 16);
    }
  };
  auto vm_lpt = [&] {
    if constexpr (BCH == 3)
      asm volatile("s_waitcnt vmcnt(7)" ::: "memory");
    else
      asm volatile("s_waitcnt vmcnt(6)" ::: "memory");
  };

  // prologue: tile 0 -> buf0, tile 1 -> buf1; wait only for tile 0
  stageA(0, 0);
  stageB(0, 0);
  stageA(1, 1);
  stageB(1, 1);
  vm_lpt();
  block_barrier();

  for (int kt = 0; kt < NT; ++kt) {
    const int cur = kt & 1;

    // front-load ALL operands for this tile into registers
    bf16x8 af[8][2], bfr[BCH][2];
#pragma unroll
    for (int ks = 0; ks < 2; ++ks) {
#pragma unroll
      for (int i = 0; i < 8; ++i) {
        const int row = m0 + 16 * i + ln;
        const int c = (ks * 4 + quad) ^ (row & 7);
        af[i][ks] =
            *(const bf16x8*)((const char*)(&As[cur][0]) + ((row * 8 + c) << 4));
      }
#pragma unroll
      for (int j = 0; j < BCH; ++j) {
        const int row = n0 + 16 * j + ln;
        const int c = (ks * 4 + quad) ^ (row & 7);
        bfr[j][ks] =
            *(const bf16x8*)((const char*)(&Bs[cur][0]) + ((row * 8 + c) << 4));
      }
    }
    asm volatile("s_waitcnt lgkmcnt(0)" ::: "memory");  // own reads executed
    block_barrier();  // ALL waves done reading buf[cur] -> safe to restage

    if (kt + 2 < NT) stageA(kt + 2, cur);
    __builtin_amdgcn_s_setprio(1);
#pragma unroll
    for (int i = 0; i < 8; ++i)
#pragma unroll
      for (int j = 0; j < BCH; ++j)
        acc[i][j] = __builtin_amdgcn_mfma_f32_16x16x32_bf16(af[i][0], bfr[j][0],
                                                            acc[i][j], 0, 0, 0);
    __builtin_amdgcn_s_setprio(0);
    if (kt + 2 < NT) stageB(kt + 2, cur);
    __builtin_amdgcn_s_setprio(1);
#pragma unroll
    for (int i = 0; i < 8; ++i)
#pragma unroll
      for (int j = 0; j < BCH; ++j)
        acc[i][j] = __builtin_amdgcn_mfma_f32_16x16x32_bf16(af[i][1], bfr[j][1],
                                                            acc[i][j], 0, 0, 0);
    __builtin_amdgcn_s_setprio(0);

    // tile kt+1 must be resident for next iter; keep kt+2's loads in flight.
    if (kt + 2 < NT)
      vm_lpt();
    else
      asm volatile("s_waitcnt vmcnt(0)" ::: "memory");  // tail: full drain
    block_barrier();
  }

#pragma unroll
  for (int i = 0; i < 8; ++i) {
    const int rowg = bm * 256 + m0 + 16 * i + quad * 4;
#pragma unroll
    for (int j = 0; j < BCH; ++j) {
      const int cb   = bn * (BCH * 64) + n0 + 16 * j;  // wave-uniform
      const int colg = cb + ln;
      const float bb = bias[colg];
      if (WRITE_VT && cb >= 2 * DM) {
        // V third: transposed write into Vt_g[(b*16+h)*128+d][t]
        const int vrow = ((rowg >> 10) << 11) + (colg - 2 * DM);
        bf16x4 v = {(bf16_t)(acc[i][j][0] + bb), (bf16_t)(acc[i][j][1] + bb),
                    (bf16_t)(acc[i][j][2] + bb), (bf16_t)(acc[i][j][3] + bb)};
        *(bf16x4*)(vt + (size_t)vrow * TT + (rowg & (TT - 1))) = v;
      } else {
#pragma unroll
        for (int r = 0; r < 4; ++r) {
          float val = acc[i][j][r] + bb;
          if (OUT_BF16)
            ((bf16_t*)out)[(size_t)(rowg + r) * N + colg] = (bf16_t)val;
          else
            ((float*)out)[(size_t)(rowg + r) * N + colg] = val;
        }
      }
    }
  }
}

// ---------------------------------------------------------------------------
// Flash attention, causal, FIXED-SHIFT softmax. 256 thr / 4 waves / QBLK=64 /
// KVBLK=64, dbuf K/V, issue-early staging, counted vmcnt(8), snake qt mapping
// (co-resident quartets sum to exactly 30 chunks).
// ---------------------------------------------------------------------------
__global__ __launch_bounds__(256, 2) void attn_kernel(
    const bf16_t* __restrict__ qkv, const bf16_t* __restrict__ Vt_g,
    bf16_t* __restrict__ attout) {
  const int bx = blockIdx.x;
  const int bh = bx & 63;
  const int j_  = bx >> 6;
  const int rr  = j_ >> 2, cc_ = j_ & 3;
  const int qt  = (rr & 1) ? (rr * 4 + (3 - cc_)) : (rr * 4 + cc_);
  const int b  = bh >> 4;
  const int h  = bh & 15;
  const int tid  = threadIdx.x;
  const int lane = tid & 63;
  const int wave = tid >> 6;
  const int ln   = lane & 15;
  const int quad = lane >> 4;

  __shared__ __align__(16) bf16_t Ks[2][64 * 128];
  __shared__ __align__(16) bf16_t Vs[2][128 * 64];
  __shared__ __align__(16) bf16_t Ps[4 * 16 * 64];

  const float scale = 0.08838834764831845f;
  const float SHIFT = 12.0f;
  const int q0 = qt * 64 + wave * 16;

  bf16x8 aq[4];
  {
    const bf16_t* qrow = qkv + (size_t)(b * TT + q0 + ln) * DQKV + h * DH;
#pragma unroll
    for (int kt = 0; kt < 4; ++kt)
      aq[kt] = *(const bf16x8*)(qrow + kt * 32 + quad * 8);
  }

  auto stage = [&](int c, int buf) {
    const int kc = c * 64;
#pragma unroll
    for (int j = 0; j < 4; ++j) {
      const int fb = j * 256 + wave * 64;
      const int l  = fb + lane;
      {
        const int row = l >> 4, cc = l & 15;
        const int gc  = cc ^ (row & 7);
        const bf16_t* g =
            qkv + (size_t)(b * TT + kc + row) * DQKV + DM + h * DH + gc * 8;
        async16(g, (char*)(&Ks[buf][0]) + fb * 16);
      }
      {
        const int d = l >> 3, cc = l & 7;
        const int gc = cc ^ (d & 7);
        const bf16_t* g = Vt_g + (size_t)(bh * DH + d) * TT + kc + gc * 8;
        async16(g, (char*)(&Vs[buf][0]) + fb * 16);
      }
    }
  };

  f32x4 o[8] = {};
  float lp[4] = {0.f, 0.f, 0.f, 0.f};

  stage(0, 0);

  for (int c = 0; c <= qt; ++c) {
    const int cur = c & 1;
    const char* Kc = (const char*)(&Ks[cur][0]);
    const char* Vc = (const char*)(&Vs[cur][0]);

    asm volatile("s_waitcnt lgkmcnt(0)" ::: "memory");
    block_barrier();
    if (c < qt) {
      stage(c + 1, cur ^ 1);
      asm volatile("s_waitcnt vmcnt(8)" ::: "memory");
    } else {
      asm volatile("s_waitcnt vmcnt(0)" ::: "memory");
    }
    block_barrier();

    f32x4 sacc[4];
    __builtin_amdgcn_s_setprio(1);
#pragma unroll
    for (int jt = 0; jt < 4; ++jt) {
      sacc[jt] = (f32x4){0.f, 0.f, 0.f, 0.f};
#pragma unroll
      for (int kt = 0; kt < 4; ++kt) {
        const int row = jt * 16 + ln;
        const int sc  = (kt * 4 + quad) ^ (row & 7);
        bf16x8 bk = *(const bf16x8*)(Kc + row * 256 + sc * 16);
        sacc[jt] = __builtin_amdgcn_mfma_f32_16x16x32_bf16(aq[kt], bk,
                                                           sacc[jt], 0, 0, 0);
      }
    }
    __builtin_amdgcn_s_setprio(0);

    const int kc = c * 64;
    const bool diag = (c == qt);
#pragma unroll
    for (int jt = 0; jt < 4; ++jt) {
      const int colg = kc + jt * 16 + ln;
#pragma unroll
      for (int r = 0; r < 4; ++r) {
        float sv = sacc[jt][r] * scale - SHIFT;
        if (diag && colg > q0 + quad * 4 + r) sv = -1e30f;
        float pv = __expf(sv);
        lp[r] += pv;
        const int row = quad * 4 + r;
        const int col = jt * 16 + ln;
        const int sc  = (col >> 3) ^ (row & 7);
        Ps[wave * 1024 + row * 64 + sc * 8 + (col & 7)] = (bf16_t)pv;
      }
    }

    __builtin_amdgcn_s_setprio(1);
#pragma unroll
    for (int ks = 0; ks < 2; ++ks) {
      const int psc = (ks * 4 + quad) ^ (ln & 7);
      bf16x8 ap =
          *(const bf16x8*)((const char*)Ps + wave * 2048 + ln * 128 + psc * 16);
#pragma unroll
      for (int nt = 0; nt < 8; ++nt) {
        const int row = nt * 16 + ln;
        const int sc  = (ks * 4 + quad) ^ (row & 7);
        bf16x8 bv = *(const bf16x8*)(Vc + row * 128 + sc * 16);
        o[nt] = __builtin_amdgcn_mfma_f32_16x16x32_bf16(ap, bv, o[nt], 0, 0, 0);
      }
    }
    __builtin_amdgcn_s_setprio(0);
  }

#pragma unroll
  for (int off = 1; off < 16; off <<= 1)
#pragma unroll
    for (int r = 0; r < 4; ++r) lp[r] += __shfl_xor(lp[r], off, 64);

#pragma unroll
  for (int r = 0; r < 4; ++r) {
    float inv = 1.0f / lp[r];
    int t = q0 + quad * 4 + r;
    bf16_t* orow = attout + (size_t)(b * TT + t) * DM + h * DH;
#pragma unroll
    for (int nt = 0; nt < 8; ++nt)
      orow[nt * 16 + ln] = (bf16_t)(o[nt][r] * inv);
  }
}

// ---------------------------------------------------------------------------
extern "C" void kernel_launch(void* const* d_in, const int* in_sizes, int n_in,
                              void* d_out, int out_size, void* d_ws,
                              size_t ws_size, hipStream_t stream) {
  const float* x     = (const float*)d_in[0];
  const float* w_qkv = (const float*)d_in[1];
  const float* b_qkv = (const float*)d_in[2];
  const float* w_out = (const float*)d_in[3];
  const float* b_out = (const float*)d_in[4];
  float* out = (float*)d_out;

  char* ws = (char*)d_ws;
  bf16_t* qkv    = (bf16_t*)(ws);
  bf16_t* wqkv_t = (bf16_t*)(ws + 50331648);
  bf16_t* wout_t = (bf16_t*)(ws + 75497472);
  bf16_t* xb     = (bf16_t*)(ws + 83886080);
  bf16_t* attout = xb;

  const bool fuse_vt = (ws_size >= 117440512);
  bf16_t* Vt_g = fuse_vt ? (bf16_t*)(ws + 100663296) : wqkv_t;

  prep_kernel<<<dim3(8192), dim3(256), 0, stream>>>(x, xb, w_qkv, wqkv_t,
                                                    w_out, wout_t);
  if (fuse_vt) {
    gemm_big_kernel<true, 3, true><<<dim3(512), dim3(512), 0, stream>>>(
        xb, wqkv_t, b_qkv, qkv, Vt_g, 4096, 6144, 2048, 16);
  } else {
    gemm_big_kernel<true, 3, false><<<dim3(512), dim3(512), 0, stream>>>(
        xb, wqkv_t, b_qkv, qkv, nullptr, 4096, 6144, 2048, 16);
    v_transpose_kernel<<<dim3(2, 16, 64), dim3(256), 0, stream>>>(qkv, Vt_g);
  }
  attn_kernel<<<dim3(1024), dim3(256), 0, stream>>>(qkv, Vt_g, attout);
  gemm_big_kernel<false, 2, false><<<dim3(256), dim3(512), 0, stream>>>(
      attout, wout_t, b_out, out, nullptr, 4096, 2048, 2048, 16);
}

// Round 10
// 318.818 us; speedup vs baseline: 1.1350x; 1.0417x over previous
//
#include <hip/hip_runtime.h>
#include <hip/hip_bf16.h>
#include <math.h>

#define DM    2048
#define DQKV  6144
#define NH    16
#define DH    128
#define TT    1024
#define BB    4

typedef __bf16 bf16_t;
typedef __bf16 bf16x4 __attribute__((ext_vector_type(4)));
typedef __bf16 bf16x8 __attribute__((ext_vector_type(8)));
typedef float  f32x4  __attribute__((ext_vector_type(4)));

__device__ __forceinline__ void async16(const void* g, void* lds) {
  __builtin_amdgcn_global_load_lds(
      (const __attribute__((address_space(1))) unsigned int*)g,
      (__attribute__((address_space(3))) unsigned int*)lds, 16, 0, 0);
}

// raw s_barrier with compiler memory fences (no vmcnt/lgkm drain emitted)
__device__ __forceinline__ void block_barrier() {
  asm volatile("" ::: "memory");
  __builtin_amdgcn_s_barrier();
  asm volatile("" ::: "memory");
}

// ---------------------------------------------------------------------------
// PREP (fused, 1 launch): blocks [0,4096) cast x->xb; [4096,7168) transpose
// w_qkv; [7168,8192) transpose w_out. Transpose write side vectorized to
// 2x16B stores/thread (was 4x8B); LDS fill uses bf16x4 stores (was scalar).
// ---------------------------------------------------------------------------
__global__ __launch_bounds__(256) void prep_kernel(
    const float* __restrict__ x, bf16_t* __restrict__ xb,
    const float* __restrict__ w_qkv, bf16_t* __restrict__ wqkv_t,
    const float* __restrict__ w_out, bf16_t* __restrict__ wout_t) {
  const int tid = threadIdx.x;
  const int bx = blockIdx.x;
  if (bx < 4096) {  // cast fp32 -> bf16, 8 elems/thread
    const size_t i = ((size_t)bx * 256 + tid) * 8;
    float4 a = *(const float4*)(x + i);
    float4 b = *(const float4*)(x + i + 4);
    bf16x8 o = {(bf16_t)a.x, (bf16_t)a.y, (bf16_t)a.z, (bf16_t)a.w,
                (bf16_t)b.x, (bf16_t)b.y, (bf16_t)b.z, (bf16_t)b.w};
    *(bf16x8*)(xb + i) = o;
    return;
  }
  // W[K][N] fp32 -> Wt[N][K] bf16, 64x64 tiles
  __shared__ bf16_t tile[64][72];
  const float* W;
  bf16_t* Wt;
  int K, N, tn, tk;
  if (bx < 7168) {
    const int t = bx - 4096;
    W = w_qkv; Wt = wqkv_t; K = 2048; N = 6144;
    tn = (t % 96) * 64; tk = (t / 96) * 64;
  } else {
    const int t = bx - 7168;
    W = w_out; Wt = wout_t; K = 2048; N = 2048;
    tn = (t % 32) * 64; tk = (t / 32) * 64;
  }
  {
    int r = tid >> 2, c0 = (tid & 3) * 16;
    const float* src = W + (size_t)(tk + r) * N + tn + c0;
#pragma unroll
    for (int j = 0; j < 4; ++j) {
      float4 v = *(const float4*)(src + j * 4);
      bf16x4 t = {(bf16_t)v.x, (bf16_t)v.y, (bf16_t)v.z, (bf16_t)v.w};
      *(bf16x4*)&tile[r][c0 + j * 4] = t;
    }
  }
  __syncthreads();
  {
    int n = tid >> 2, c0 = (tid & 3) * 16;
    bf16_t* dst = Wt + (size_t)(tn + n) * K + tk + c0;
    bf16x8 t0 = {tile[c0 + 0][n], tile[c0 + 1][n], tile[c0 + 2][n],
                 tile[c0 + 3][n], tile[c0 + 4][n], tile[c0 + 5][n],
                 tile[c0 + 6][n], tile[c0 + 7][n]};
    bf16x8 t1 = {tile[c0 + 8][n],  tile[c0 + 9][n],  tile[c0 + 10][n],
                 tile[c0 + 11][n], tile[c0 + 12][n], tile[c0 + 13][n],
                 tile[c0 + 14][n], tile[c0 + 15][n]};
    *(bf16x8*)(dst) = t0;
    *(bf16x8*)(dst + 8) = t1;
  }
}

// ---------------------------------------------------------------------------
// V transpose (FALLBACK only, when ws too small for non-aliased Vt_g).
// ---------------------------------------------------------------------------
__global__ __launch_bounds__(256) void v_transpose_kernel(
    const bf16_t* __restrict__ qkv, bf16_t* __restrict__ Vt_g) {
  __shared__ bf16_t tile[64][72];
  const int tid = threadIdx.x;
  const int dt = blockIdx.x;
  const int tt = blockIdx.y;
  const int bh = blockIdx.z;
  const int b = bh >> 4, h = bh & 15;
  {
    int r = tid >> 2, c0 = (tid & 3) * 16;
    const bf16_t* src =
        qkv + (size_t)(b * TT + tt * 64 + r) * DQKV + 2 * DM + h * DH + dt * 64 + c0;
    *(bf16x8*)&tile[r][c0]     = *(const bf16x8*)(src);
    *(bf16x8*)&tile[r][c0 + 8] = *(const bf16x8*)(src + 8);
  }
  __syncthreads();
  {
    int n = tid >> 2, c0 = (tid & 3) * 16;
    bf16_t* dst = Vt_g + (size_t)(bh * DH + dt * 64 + n) * TT + tt * 64 + c0;
#pragma unroll
    for (int j = 0; j < 4; ++j) {
      bf16x4 t = {tile[c0 + j * 4 + 0][n], tile[c0 + j * 4 + 1][n],
                  tile[c0 + j * 4 + 2][n], tile[c0 + j * 4 + 3][n]};
      *(bf16x4*)(dst + j * 4) = t;
    }
  }
}

// ---------------------------------------------------------------------------
// GEMM 256 x (BCH*64), BK=64, 512 thr / 8 waves (2M x 4N).
// VERIFIED counted-vmcnt schedule (899 TF). Per K-tile: front-load all
// ds_read operands -> lgkmcnt(0) -> barrier -> stage A(kt+2) -> MFMA ks0 ->
// stage B(kt+2) -> MFMA ks1 -> vmcnt(LPT) -> barrier. Tail drains vmcnt(0).
// Do NOT restructure this loop: 8-phase (r2) and interleaved-cluster (r7)
// variants both regressed ~20%.
// WRITE_VT: V-third columns written transposed into Vt_g (fuses v_transpose).
// ---------------------------------------------------------------------------
template <bool OUT_BF16, int BCH, bool WRITE_VT>
__global__ __launch_bounds__(512, 2) void gemm_big_kernel(
    const bf16_t* __restrict__ A, const bf16_t* __restrict__ Bt,
    const float* __restrict__ bias, void* __restrict__ out,
    bf16_t* __restrict__ vt, int M, int N, int K, int nbm) {
  __shared__ __align__(16) bf16_t As[2][256 * 64];
  __shared__ __align__(16) bf16_t Bs[2][BCH * 64 * 64];

  const int tid  = threadIdx.x;
  const int lane = tid & 63;
  const int wave = tid >> 6;
  const int ln   = lane & 15;
  const int quad = lane >> 4;

  const int cpx = gridDim.x >> 3;
  const int wg  = (blockIdx.x & 7) * cpx + (blockIdx.x >> 3);
  const int bm  = wg & (nbm - 1);
  const int bn  = wg / nbm;

  const bf16_t* Abase = A + (size_t)bm * 256 * K;
  const bf16_t* Bbase = Bt + (size_t)bn * (BCH * 64) * K;

  const int m0 = (wave >> 2) * 128;
  const int n0 = (wave & 3) * (BCH * 16);

  f32x4 acc[8][BCH] = {};

  const int NT = K >> 6;

  auto stageA = [&](int kt, int d) {
#pragma unroll
    for (int s = 0; s < 4; ++s) {
      const int fb  = s * 512 + wave * 64;
      const int f   = fb + lane;
      const int row = f >> 3, c = f & 7;
      const int gc  = c ^ (row & 7);
      async16(Abase + (size_t)row * K + kt * 64 + gc * 8,
              (char*)(&As[d][0]) + fb * 16);
    }
  };
  auto stageB = [&](int kt, int d) {
#pragma unroll
    for (int s = 0; s < BCH; ++s) {
      const int fb  = s * 512 + wave * 64;
      const int f   = fb + lane;
      const int row = f >> 3, c = f & 7;
      const int gc  = c ^ (row & 7);
      async16(Bbase + (size_t)row * K + kt * 64 + gc * 8,
              (char*)(&Bs[d][0]) + fb * 16);
    }
  };
  auto vm_lpt = [&] {
    if constexpr (BCH == 3)
      asm volatile("s_waitcnt vmcnt(7)" ::: "memory");
    else
      asm volatile("s_waitcnt vmcnt(6)" ::: "memory");
  };

  stageA(0, 0);
  stageB(0, 0);
  stageA(1, 1);
  stageB(1, 1);
  vm_lpt();
  block_barrier();

  for (int kt = 0; kt < NT; ++kt) {
    const int cur = kt & 1;

    bf16x8 af[8][2], bfr[BCH][2];
#pragma unroll
    for (int ks = 0; ks < 2; ++ks) {
#pragma unroll
      for (int i = 0; i < 8; ++i) {
        const int row = m0 + 16 * i + ln;
        const int c = (ks * 4 + quad) ^ (row & 7);
        af[i][ks] =
            *(const bf16x8*)((const char*)(&As[cur][0]) + ((row * 8 + c) << 4));
      }
#pragma unroll
      for (int j = 0; j < BCH; ++j) {
        const int row = n0 + 16 * j + ln;
        const int c = (ks * 4 + quad) ^ (row & 7);
        bfr[j][ks] =
            *(const bf16x8*)((const char*)(&Bs[cur][0]) + ((row * 8 + c) << 4));
      }
    }
    asm volatile("s_waitcnt lgkmcnt(0)" ::: "memory");
    block_barrier();

    if (kt + 2 < NT) stageA(kt + 2, cur);
    __builtin_amdgcn_s_setprio(1);
#pragma unroll
    for (int i = 0; i < 8; ++i)
#pragma unroll
      for (int j = 0; j < BCH; ++j)
        acc[i][j] = __builtin_amdgcn_mfma_f32_16x16x32_bf16(af[i][0], bfr[j][0],
                                                            acc[i][j], 0, 0, 0);
    __builtin_amdgcn_s_setprio(0);
    if (kt + 2 < NT) stageB(kt + 2, cur);
    __builtin_amdgcn_s_setprio(1);
#pragma unroll
    for (int i = 0; i < 8; ++i)
#pragma unroll
      for (int j = 0; j < BCH; ++j)
        acc[i][j] = __builtin_amdgcn_mfma_f32_16x16x32_bf16(af[i][1], bfr[j][1],
                                                            acc[i][j], 0, 0, 0);
    __builtin_amdgcn_s_setprio(0);

    if (kt + 2 < NT)
      vm_lpt();
    else
      asm volatile("s_waitcnt vmcnt(0)" ::: "memory");
    block_barrier();
  }

#pragma unroll
  for (int i = 0; i < 8; ++i) {
    const int rowg = bm * 256 + m0 + 16 * i + quad * 4;
#pragma unroll
    for (int j = 0; j < BCH; ++j) {
      const int cb   = bn * (BCH * 64) + n0 + 16 * j;
      const int colg = cb + ln;
      const float bb = bias[colg];
      if (WRITE_VT && cb >= 2 * DM) {
        const int vrow = ((rowg >> 10) << 11) + (colg - 2 * DM);
        bf16x4 v = {(bf16_t)(acc[i][j][0] + bb), (bf16_t)(acc[i][j][1] + bb),
                    (bf16_t)(acc[i][j][2] + bb), (bf16_t)(acc[i][j][3] + bb)};
        *(bf16x4*)(vt + (size_t)vrow * TT + (rowg & (TT - 1))) = v;
      } else {
#pragma unroll
        for (int r = 0; r < 4; ++r) {
          float val = acc[i][j][r] + bb;
          if (OUT_BF16)
            ((bf16_t*)out)[(size_t)(rowg + r) * N + colg] = (bf16_t)val;
          else
            ((float*)out)[(size_t)(rowg + r) * N + colg] = val;
        }
      }
    }
  }
}

// ---------------------------------------------------------------------------
// GEMM 128x128 (gemm2): same verified counted-vmcnt schedule, smaller
// geometry. 256 thr / 4 waves (2M x 2N, per-wave 64x64). LDS = 4x16 KB =
// 64 KB -> 2 blocks/CU; grid 32x16 = 512 blocks = 2 rounds of 2-resident.
// Mechanism: per-tile wall in this schedule is ~4400cy of which only ~1860
// is MFMA; at 1 block/CU (old gemm2) the rest is exposed (measured ~59us =
// 32 tiles x 4400cy). With 2 co-resident blocks the serialization of one
// overlaps the MFMA of the other. 8 loads/thread/tile -> vmcnt(8).
// ---------------------------------------------------------------------------
__global__ __launch_bounds__(256, 2) void gemm128_kernel(
    const bf16_t* __restrict__ A, const bf16_t* __restrict__ Bt,
    const float* __restrict__ bias, float* __restrict__ out,
    int M, int N, int K, int nbm) {
  __shared__ __align__(16) bf16_t As[2][128 * 64];
  __shared__ __align__(16) bf16_t Bs[2][128 * 64];

  const int tid  = threadIdx.x;
  const int lane = tid & 63;
  const int wave = tid >> 6;
  const int ln   = lane & 15;
  const int quad = lane >> 4;

  const int cpx = gridDim.x >> 3;
  const int wg  = (blockIdx.x & 7) * cpx + (blockIdx.x >> 3);
  const int bm  = wg & (nbm - 1);   // nbm = 32 (power of two)
  const int bn  = wg / nbm;

  const bf16_t* Abase = A + (size_t)bm * 128 * K;
  const bf16_t* Bbase = Bt + (size_t)bn * 128 * K;

  const int m0 = (wave >> 1) * 64;  // 2 M-waves
  const int n0 = (wave & 1) * 64;   // 2 N-waves

  f32x4 acc[4][4] = {};

  const int NT = K >> 6;

  // 128x64 tile = 1024 16B-chunks; 256 thr x 4 = 1024.
  auto stageA = [&](int kt, int d) {
#pragma unroll
    for (int s = 0; s < 4; ++s) {
      const int fb  = s * 256 + wave * 64;
      const int f   = fb + lane;
      const int row = f >> 3, c = f & 7;
      const int gc  = c ^ (row & 7);
      async16(Abase + (size_t)row * K + kt * 64 + gc * 8,
              (char*)(&As[d][0]) + fb * 16);
    }
  };
  auto stageB = [&](int kt, int d) {
#pragma unroll
    for (int s = 0; s < 4; ++s) {
      const int fb  = s * 256 + wave * 64;
      const int f   = fb + lane;
      const int row = f >> 3, c = f & 7;
      const int gc  = c ^ (row & 7);
      async16(Bbase + (size_t)row * K + kt * 64 + gc * 8,
              (char*)(&Bs[d][0]) + fb * 16);
    }
  };

  stageA(0, 0);
  stageB(0, 0);
  stageA(1, 1);
  stageB(1, 1);
  asm volatile("s_waitcnt vmcnt(8)" ::: "memory");
  block_barrier();

  for (int kt = 0; kt < NT; ++kt) {
    const int cur = kt & 1;

    bf16x8 af[4][2], bfr[4][2];
#pragma unroll
    for (int ks = 0; ks < 2; ++ks) {
#pragma unroll
      for (int i = 0; i < 4; ++i) {
        const int row = m0 + 16 * i + ln;
        const int c = (ks * 4 + quad) ^ (row & 7);
        af[i][ks] =
            *(const bf16x8*)((const char*)(&As[cur][0]) + ((row * 8 + c) << 4));
      }
#pragma unroll
      for (int j = 0; j < 4; ++j) {
        const int row = n0 + 16 * j + ln;
        const int c = (ks * 4 + quad) ^ (row & 7);
        bfr[j][ks] =
            *(const bf16x8*)((const char*)(&Bs[cur][0]) + ((row * 8 + c) << 4));
      }
    }
    asm volatile("s_waitcnt lgkmcnt(0)" ::: "memory");
    block_barrier();

    if (kt + 2 < NT) stageA(kt + 2, cur);
    __builtin_amdgcn_s_setprio(1);
#pragma unroll
    for (int i = 0; i < 4; ++i)
#pragma unroll
      for (int j = 0; j < 4; ++j)
        acc[i][j] = __builtin_amdgcn_mfma_f32_16x16x32_bf16(af[i][0], bfr[j][0],
                                                            acc[i][j], 0, 0, 0);
    __builtin_amdgcn_s_setprio(0);
    if (kt + 2 < NT) stageB(kt + 2, cur);
    __builtin_amdgcn_s_setprio(1);
#pragma unroll
    for (int i = 0; i < 4; ++i)
#pragma unroll
      for (int j = 0; j < 4; ++j)
        acc[i][j] = __builtin_amdgcn_mfma_f32_16x16x32_bf16(af[i][1], bfr[j][1],
                                                            acc[i][j], 0, 0, 0);
    __builtin_amdgcn_s_setprio(0);

    if (kt + 2 < NT)
      asm volatile("s_waitcnt vmcnt(8)" ::: "memory");
    else
      asm volatile("s_waitcnt vmcnt(0)" ::: "memory");
    block_barrier();
  }

#pragma unroll
  for (int i = 0; i < 4; ++i) {
    const int rowg = bm * 128 + m0 + 16 * i + quad * 4;
#pragma unroll
    for (int j = 0; j < 4; ++j) {
      const int colg = bn * 128 + n0 + 16 * j + ln;
      const float bb = bias[colg];
#pragma unroll
      for (int r = 0; r < 4; ++r)
        out[(size_t)(rowg + r) * N + colg] = acc[i][j][r] + bb;
    }
  }
}

// ---------------------------------------------------------------------------
// Flash attention, causal, FIXED-SHIFT softmax. 256 thr / 4 waves / QBLK=64 /
// KVBLK=64, dbuf K/V, issue-early staging, counted vmcnt(8), snake qt mapping.
// ---------------------------------------------------------------------------
__global__ __launch_bounds__(256, 2) void attn_kernel(
    const bf16_t* __restrict__ qkv, const bf16_t* __restrict__ Vt_g,
    bf16_t* __restrict__ attout) {
  const int bx = blockIdx.x;
  const int bh = bx & 63;
  const int j_  = bx >> 6;
  const int rr  = j_ >> 2, cc_ = j_ & 3;
  const int qt  = (rr & 1) ? (rr * 4 + (3 - cc_)) : (rr * 4 + cc_);
  const int b  = bh >> 4;
  const int h  = bh & 15;
  const int tid  = threadIdx.x;
  const int lane = tid & 63;
  const int wave = tid >> 6;
  const int ln   = lane & 15;
  const int quad = lane >> 4;

  __shared__ __align__(16) bf16_t Ks[2][64 * 128];
  __shared__ __align__(16) bf16_t Vs[2][128 * 64];
  __shared__ __align__(16) bf16_t Ps[4 * 16 * 64];

  const float scale = 0.08838834764831845f;
  const float SHIFT = 12.0f;
  const int q0 = qt * 64 + wave * 16;

  bf16x8 aq[4];
  {
    const bf16_t* qrow = qkv + (size_t)(b * TT + q0 + ln) * DQKV + h * DH;
#pragma unroll
    for (int kt = 0; kt < 4; ++kt)
      aq[kt] = *(const bf16x8*)(qrow + kt * 32 + quad * 8);
  }

  auto stage = [&](int c, int buf) {
    const int kc = c * 64;
#pragma unroll
    for (int j = 0; j < 4; ++j) {
      const int fb = j * 256 + wave * 64;
      const int l  = fb + lane;
      {
        const int row = l >> 4, cc = l & 15;
        const int gc  = cc ^ (row & 7);
        const bf16_t* g =
            qkv + (size_t)(b * TT + kc + row) * DQKV + DM + h * DH + gc * 8;
        async16(g, (char*)(&Ks[buf][0]) + fb * 16);
      }
      {
        const int d = l >> 3, cc = l & 7;
        const int gc = cc ^ (d & 7);
        const bf16_t* g = Vt_g + (size_t)(bh * DH + d) * TT + kc + gc * 8;
        async16(g, (char*)(&Vs[buf][0]) + fb * 16);
      }
    }
  };

  f32x4 o[8] = {};
  float lp[4] = {0.f, 0.f, 0.f, 0.f};

  stage(0, 0);

  for (int c = 0; c <= qt; ++c) {
    const int cur = c & 1;
    const char* Kc = (const char*)(&Ks[cur][0]);
    const char* Vc = (const char*)(&Vs[cur][0]);

    asm volatile("s_waitcnt lgkmcnt(0)" ::: "memory");
    block_barrier();
    if (c < qt) {
      stage(c + 1, cur ^ 1);
      asm volatile("s_waitcnt vmcnt(8)" ::: "memory");
    } else {
      asm volatile("s_waitcnt vmcnt(0)" ::: "memory");
    }
    block_barrier();

    f32x4 sacc[4];
    __builtin_amdgcn_s_setprio(1);
#pragma unroll
    for (int jt = 0; jt < 4; ++jt) {
      sacc[jt] = (f32x4){0.f, 0.f, 0.f, 0.f};
#pragma unroll
      for (int kt = 0; kt < 4; ++kt) {
        const int row = jt * 16 + ln;
        const int sc  = (kt * 4 + quad) ^ (row & 7);
        bf16x8 bk = *(const bf16x8*)(Kc + row * 256 + sc * 16);
        sacc[jt] = __builtin_amdgcn_mfma_f32_16x16x32_bf16(aq[kt], bk,
                                                           sacc[jt], 0, 0, 0);
      }
    }
    __builtin_amdgcn_s_setprio(0);

    const int kc = c * 64;
    const bool diag = (c == qt);
#pragma unroll
    for (int jt = 0; jt < 4; ++jt) {
      const int colg = kc + jt * 16 + ln;
#pragma unroll
      for (int r = 0; r < 4; ++r) {
        float sv = sacc[jt][r] * scale - SHIFT;
        if (diag && colg > q0 + quad * 4 + r) sv = -1e30f;
        float pv = __expf(sv);
        lp[r] += pv;
        const int row = quad * 4 + r;
        const int col = jt * 16 + ln;
        const int sc  = (col >> 3) ^ (row & 7);
        Ps[wave * 1024 + row * 64 + sc * 8 + (col & 7)] = (bf16_t)pv;
      }
    }

    __builtin_amdgcn_s_setprio(1);
#pragma unroll
    for (int ks = 0; ks < 2; ++ks) {
      const int psc = (ks * 4 + quad) ^ (ln & 7);
      bf16x8 ap =
          *(const bf16x8*)((const char*)Ps + wave * 2048 + ln * 128 + psc * 16);
#pragma unroll
      for (int nt = 0; nt < 8; ++nt) {
        const int row = nt * 16 + ln;
        const int sc  = (ks * 4 + quad) ^ (row & 7);
        bf16x8 bv = *(const bf16x8*)(Vc + row * 128 + sc * 16);
        o[nt] = __builtin_amdgcn_mfma_f32_16x16x32_bf16(ap, bv, o[nt], 0, 0, 0);
      }
    }
    __builtin_amdgcn_s_setprio(0);
  }

#pragma unroll
  for (int off = 1; off < 16; off <<= 1)
#pragma unroll
    for (int r = 0; r < 4; ++r) lp[r] += __shfl_xor(lp[r], off, 64);

#pragma unroll
  for (int r = 0; r < 4; ++r) {
    float inv = 1.0f / lp[r];
    int t = q0 + quad * 4 + r;
    bf16_t* orow = attout + (size_t)(b * TT + t) * DM + h * DH;
#pragma unroll
    for (int nt = 0; nt < 8; ++nt)
      orow[nt * 16 + ln] = (bf16_t)(o[nt][r] * inv);
  }
}

// ---------------------------------------------------------------------------
extern "C" void kernel_launch(void* const* d_in, const int* in_sizes, int n_in,
                              void* d_out, int out_size, void* d_ws,
                              size_t ws_size, hipStream_t stream) {
  const float* x     = (const float*)d_in[0];
  const float* w_qkv = (const float*)d_in[1];
  const float* b_qkv = (const float*)d_in[2];
  const float* w_out = (const float*)d_in[3];
  const float* b_out = (const float*)d_in[4];
  float* out = (float*)d_out;

  char* ws = (char*)d_ws;
  bf16_t* qkv    = (bf16_t*)(ws);
  bf16_t* wqkv_t = (bf16_t*)(ws + 50331648);
  bf16_t* wout_t = (bf16_t*)(ws + 75497472);
  bf16_t* xb     = (bf16_t*)(ws + 83886080);
  bf16_t* attout = xb;

  const bool fuse_vt = (ws_size >= 117440512);
  bf16_t* Vt_g = fuse_vt ? (bf16_t*)(ws + 100663296) : wqkv_t;

  prep_kernel<<<dim3(8192), dim3(256), 0, stream>>>(x, xb, w_qkv, wqkv_t,
                                                    w_out, wout_t);
  if (fuse_vt) {
    gemm_big_kernel<true, 3, true><<<dim3(512), dim3(512), 0, stream>>>(
        xb, wqkv_t, b_qkv, qkv, Vt_g, 4096, 6144, 2048, 16);
  } else {
    gemm_big_kernel<true, 3, false><<<dim3(512), dim3(512), 0, stream>>>(
        xb, wqkv_t, b_qkv, qkv, nullptr, 4096, 6144, 2048, 16);
    v_transpose_kernel<<<dim3(2, 16, 64), dim3(256), 0, stream>>>(qkv, Vt_g);
  }
  attn_kernel<<<dim3(1024), dim3(256), 0, stream>>>(qkv, Vt_g, attout);
  // gemm2: 128x128 tiles -> 512 blocks, 2 blocks/CU, 2 rounds.
  gemm128_kernel<<<dim3(512), dim3(256), 0, stream>>>(
      attout, wout_t, b_out, out, 4096, 2048, 2048, 32);
}